// Round 9
// baseline (61.085 us; speedup 1.0000x reference)
//
#include <hip/hip_runtime.h>
#include <hip/hip_bf16.h>

#define CRF_B 512
#define CRF_S 1024
#define CRF_L 64
#define CRF_BOS 61
#define CRF_EOS 62
#define CRF_NC 64                  // chunks per sequence
#define CRF_CK (CRF_S / CRF_NC)    // 16 steps per chunk
#define CRF_W 2                    // burn-in steps (Hilbert contraction ~0.1/step)
#define GRP 16                     // batches per wave
#define PART_BLOCKS ((CRF_B / GRP) * CRF_NC)   // 2048
#define TOT_BLOCKS (PART_BLOCKS + CRF_B)       // 2560, gold interleaved 1:4

typedef __attribute__((ext_vector_type(8))) short short8;
typedef __attribute__((ext_vector_type(4))) float f32x4;
#define UNR _Pragma("unroll")

__device__ __forceinline__ unsigned short f2bf(float x) {
    union { __hip_bfloat16 h; unsigned short u; } cv;
    cv.h = __float2bfloat16(x);
    return cv.u;
}
__device__ __forceinline__ f32x4 ntload4(const float* p) {
    return __builtin_nontemporal_load((const f32x4*)p);
}

// -------------------- gold scores (R6 version, atomic output) -----------
__device__ __forceinline__ void gold_body(
    int b, int l,
    const float* __restrict__ em, const float* __restrict__ trans,
    const int* __restrict__ tags, const float* __restrict__ mask,
    float* __restrict__ out)
{
    const float* emb = em + (size_t)b * CRF_S * CRF_L;
    const int*   tg  = tags + (size_t)b * CRF_S;
    const float* mk  = mask + (size_t)b * CRF_S;

    float acc = 0.f, msum = 0.f;
    for (int t = l; t < CRF_S; t += 64) {
        float m = mk[t];
        msum += m;
        if (t >= 1) {
            int ct = tg[t];
            int pt = tg[t - 1];
            acc += (emb[(size_t)t * CRF_L + ct] + trans[pt * CRF_L + ct]) * m;
        }
    }
    UNR
    for (int off = 32; off; off >>= 1) {
        acc  += __shfl_xor(acc, off);
        msum += __shfl_xor(msum, off);
    }
    if (l == 0) {
        int t0 = tg[0];
        acc += trans[CRF_BOS * CRF_L + t0] + emb[t0];
        int last = (int)(msum + 0.5f) - 1;
        int lt = tg[last];
        acc += trans[lt * CRF_L + CRF_EOS];
        atomicAdd(&out[b], -acc);
    }
}

// -------------------- MFMA chunked log partition, zero-shuffle ----------
// S' = E_perm(A-op, const) @ S(B-op); MFMA C/D layout IS next step's B-frag.
// Em loads (non-temporal) 3 steps ahead, exp 1 ahead, mask 2 ahead.
#define STEP(T, eeU, eeV, rawU, mU)                                             \
  {                                                                             \
    short8 Bf0, Bf1;                                                            \
    UNR for (int e = 0; e < 8; ++e) {                                           \
        Bf0[e] = (short)f2bf(val[e >> 2][e & 3]);                               \
        Bf1[e] = (short)f2bf(val[2 + (e >> 2)][e & 3]);                         \
    }                                                                           \
    UNR for (int mt = 0; mt < 4; ++mt) {                                        \
        f32x4 acc = {0.f, 0.f, 0.f, 0.f};                                       \
        acc = __builtin_amdgcn_mfma_f32_16x16x32_bf16(Af[mt][0], Bf0, acc, 0, 0, 0); \
        acc = __builtin_amdgcn_mfma_f32_16x16x32_bf16(Af[mt][1], Bf1, acc, 0, 0, 0); \
        UNR for (int r = 0; r < 4; ++r) {                                       \
            float nv = acc[r] * eeU[mt * 4 + r];                                \
            val[mt][r] = (mU > 0.5f) ? nv : val[mt][r];                         \
        }                                                                       \
    }                                                                           \
    UNR for (int i = 0; i < 16; ++i) eeV[i] = __expf(rawU[i]);                  \
    { int tl = (T) + 3; if (tl > CRF_S - 1) tl = CRF_S - 1;                     \
      int tm = (T) + 2; if (tm > te) tm = te;                                   \
      mU = mrow[tm];                                                            \
      UNR for (int mt = 0; mt < 4; ++mt) {                                      \
          f32x4 rv = ntload4(erow + (size_t)tl * CRF_L + mt * 16);              \
          UNR for (int r = 0; r < 4; ++r) rawU[mt * 4 + r] = rv[r];             \
      } }                                                                       \
    if (((T) & 7) == 0) {                                                       \
        float rsc = __shfl(val[0][0], l & 15);                                  \
        Clog += __logf(rsc);                                                    \
        float inv = 1.0f / rsc;                                                 \
        UNR for (int mt = 0; mt < 4; ++mt)                                      \
            UNR for (int r = 0; r < 4; ++r) val[mt][r] *= inv;                  \
    }                                                                           \
    if ((T) == t_mid) a0 = Clog + __logf(__shfl(val[0][0], l & 15));            \
  }

__device__ __forceinline__ void part_body(
    int pb, int l,
    const float* __restrict__ em, const float* __restrict__ trans,
    const float* __restrict__ mask, float* __restrict__ out)
{
    const int c   = pb & (CRF_NC - 1);
    const int grp = pb / CRF_NC;
    const int lj  = l & 15;
    const int g   = l >> 4;

    short8 Af[4][2];
    UNR for (int mt = 0; mt < 4; ++mt)
      UNR for (int kc = 0; kc < 2; ++kc) {
        short8 f;
        UNR for (int e = 0; e < 8; ++e) {
            int L = kc * 32 + (e >> 2) * 16 + g * 4 + (e & 3);
            f[e] = (short)f2bf(__expf(trans[L * CRF_L + mt * 16 + lj]));
        }
        Af[mt][kc] = f;
      }

    const int b = grp * GRP + lj;
    const float* erow = em + (size_t)b * (CRF_S * CRF_L) + g * 4;
    const float* mrow = mask + (size_t)b * CRF_S;

    const int t_mid = CRF_CK * c;
    int t1, te;
    float val[4][4];
    if (c == 0) {
        t1 = 1; te = CRF_CK;
        UNR for (int mt = 0; mt < 4; ++mt)
          UNR for (int r = 0; r < 4; ++r) {
            int n = mt * 16 + g * 4 + r;
            val[mt][r] = __expf(trans[CRF_BOS * CRF_L + n] + erow[mt * 16 + r]);
          }
    } else {
        t1 = t_mid - CRF_W + 1;
        te = (c == CRF_NC - 1) ? (CRF_S - 1) : (t_mid + CRF_CK);
        UNR for (int mt = 0; mt < 4; ++mt)
          UNR for (int r = 0; r < 4; ++r) val[mt][r] = 1.0f;
    }

    float Clog = 0.f, a0 = 0.f;

    float eeX[16], eeY[16], rawX[16], rawY[16], mX, mY;
    mX = mrow[t1];
    { int tn = t1 + 1; if (tn > te) tn = te; mY = mrow[tn]; }
    UNR for (int mt = 0; mt < 4; ++mt) {
        f32x4 r0 = ntload4(erow + (size_t)t1 * CRF_L + mt * 16);
        int ta = t1 + 1; if (ta > CRF_S - 1) ta = CRF_S - 1;
        int tb = t1 + 2; if (tb > CRF_S - 1) tb = CRF_S - 1;
        f32x4 r1 = ntload4(erow + (size_t)ta * CRF_L + mt * 16);
        f32x4 r2 = ntload4(erow + (size_t)tb * CRF_L + mt * 16);
        UNR for (int r = 0; r < 4; ++r) {
            eeX[mt * 4 + r]  = __expf(r0[r]);
            rawX[mt * 4 + r] = r1[r];
            rawY[mt * 4 + r] = r2[r];
        }
    }

    int t = t1;
    for (; t + 1 <= te; t += 2) {
        STEP(t,     eeX, eeY, rawX, mX);
        STEP(t + 1, eeY, eeX, rawY, mY);
    }
    if (t <= te) STEP(t, eeX, eeY, rawX, mX);

    float a1;
    if (c == CRF_NC - 1) {
        float s = 0.f;
        UNR for (int mt = 0; mt < 4; ++mt)
          UNR for (int r = 0; r < 4; ++r)
            s += val[mt][r] * __expf(trans[(mt * 16 + g * 4 + r) * CRF_L + CRF_EOS]);
        s += __shfl_xor(s, 16);
        s += __shfl_xor(s, 32);
        a1 = Clog + __logf(s);
    } else {
        a1 = Clog + __logf(__shfl(val[0][0], l & 15));
    }
    if (l < 16) atomicAdd(&out[b], a1 - a0);
}

// ---------- fused kernel: gold interleaved 1:4 among part blocks --------
// bid%5==4 -> gold (512 waves spread across the whole dispatch window);
// else part, pb = (bid/5)*4 + bid%5  (covers [0, 2048) exactly).
__global__ __launch_bounds__(64) void crf_fused(
    const float* __restrict__ em, const float* __restrict__ trans,
    const int* __restrict__ tags, const float* __restrict__ mask,
    float* __restrict__ out)
{
    const int bid = blockIdx.x;
    const int l   = threadIdx.x;
    const int q   = bid / 5;
    const int r   = bid % 5;
    if (r == 4) {
        gold_body(q, l, em, trans, tags, mask, out);
    } else {
        part_body(q * 4 + r, l, em, trans, mask, out);
    }
}

extern "C" void kernel_launch(void* const* d_in, const int* in_sizes, int n_in,
                              void* d_out, int out_size, void* d_ws, size_t ws_size,
                              hipStream_t stream) {
    const float* em    = (const float*)d_in[0];
    const float* trans = (const float*)d_in[1];
    const int*   tags  = (const int*)d_in[2];
    const float* mask  = (const float*)d_in[3];
    float* out  = (float*)d_out;

    hipMemsetAsync(out, 0, CRF_B * sizeof(float), stream);
    crf_fused<<<TOT_BLOCKS, 64, 0, stream>>>(em, trans, tags, mask, out);
}

// Round 10
// 52.795 us; speedup vs baseline: 1.1570x; 1.1570x over previous
//
#include <hip/hip_runtime.h>
#include <hip/hip_bf16.h>

#define CRF_B 512
#define CRF_S 1024
#define CRF_L 64
#define CRF_BOS 61
#define CRF_EOS 62
#define CRF_NC 64                  // chunks per sequence
#define CRF_CK (CRF_S / CRF_NC)    // 16 steps per chunk
#define GRP 16                     // batches per wave
#define PART_BLOCKS ((CRF_B / GRP) * CRF_NC)   // 2048

typedef __attribute__((ext_vector_type(8))) short short8;
typedef __attribute__((ext_vector_type(4))) float f32x4;
#define UNR _Pragma("unroll")

__device__ __forceinline__ unsigned short f2bf(float x) {
    union { __hip_bfloat16 h; unsigned short u; } cv;
    cv.h = __float2bfloat16(x);
    return cv.u;
}

// -------------------- gold scores (R6 version, atomic output) -----------
__device__ __forceinline__ void gold_body(
    int b, int l,
    const float* __restrict__ em, const float* __restrict__ trans,
    const int* __restrict__ tags, const float* __restrict__ mask,
    float* __restrict__ out)
{
    const float* emb = em + (size_t)b * CRF_S * CRF_L;
    const int*   tg  = tags + (size_t)b * CRF_S;
    const float* mk  = mask + (size_t)b * CRF_S;

    float acc = 0.f, msum = 0.f;
    for (int t = l; t < CRF_S; t += 64) {
        float m = mk[t];
        msum += m;
        if (t >= 1) {
            int ct = tg[t];
            int pt = tg[t - 1];
            acc += (emb[(size_t)t * CRF_L + ct] + trans[pt * CRF_L + ct]) * m;
        }
    }
    UNR
    for (int off = 32; off; off >>= 1) {
        acc  += __shfl_xor(acc, off);
        msum += __shfl_xor(msum, off);
    }
    if (l == 0) {
        int t0 = tg[0];
        acc += trans[CRF_BOS * CRF_L + t0] + emb[t0];
        int last = (int)(msum + 0.5f) - 1;
        int lt = tg[last];
        acc += trans[lt * CRF_L + CRF_EOS];
        atomicAdd(&out[b], -acc);
    }
}

// -------------------- MFMA chunked log partition, 4-deep prefetch -------
// S' = E_perm(A-op, const) @ S(B-op); MFMA C/D layout IS next step's B-frag.
// FOUR rotating raw-em register buffers: loads for T+4 issue at step T; exp
// for T+1 computed at T. The vmcnt wait at step T covers a load ~3.5 steps
// old (~17 KB/wave in flight). Mask slots rotate at the same depth.
#define STEP4(T, eeU, eeV, RE, RL, MS)                                          \
  {                                                                             \
    short8 Bf0, Bf1;                                                            \
    UNR for (int e = 0; e < 8; ++e) {                                           \
        Bf0[e] = (short)f2bf(val[e >> 2][e & 3]);                               \
        Bf1[e] = (short)f2bf(val[2 + (e >> 2)][e & 3]);                         \
    }                                                                           \
    UNR for (int mt = 0; mt < 4; ++mt) {                                        \
        f32x4 acc = {0.f, 0.f, 0.f, 0.f};                                       \
        acc = __builtin_amdgcn_mfma_f32_16x16x32_bf16(Af[mt][0], Bf0, acc, 0, 0, 0); \
        acc = __builtin_amdgcn_mfma_f32_16x16x32_bf16(Af[mt][1], Bf1, acc, 0, 0, 0); \
        UNR for (int r = 0; r < 4; ++r) {                                       \
            float nv = acc[r] * eeU[mt * 4 + r];                                \
            val[mt][r] = (MS > 0.5f) ? nv : val[mt][r];                         \
        }                                                                       \
    }                                                                           \
    UNR for (int i = 0; i < 16; ++i) eeV[i] = __expf(RE[i]);                    \
    { int tl = (T) + 4; if (tl > CRF_S - 1) tl = CRF_S - 1;                     \
      int tm = (T) + 4; if (tm > te) tm = te;                                   \
      MS = mrow[tm];                                                            \
      UNR for (int mt = 0; mt < 4; ++mt) {                                      \
          f32x4 rv = *(const f32x4*)(erow + (size_t)tl * CRF_L + mt * 16);      \
          UNR for (int r = 0; r < 4; ++r) RL[mt * 4 + r] = rv[r];               \
      } }                                                                       \
    if (((T) & 7) == 0) {                                                       \
        float rsc = __shfl(val[0][0], l & 15);                                  \
        Clog += __logf(rsc);                                                    \
        float inv = 1.0f / rsc;                                                 \
        UNR for (int mt = 0; mt < 4; ++mt)                                      \
            UNR for (int r = 0; r < 4; ++r) val[mt][r] *= inv;                  \
    }                                                                           \
    if ((T) == t_mid) a0 = Clog + __logf(__shfl(val[0][0], l & 15));            \
  }

__device__ __forceinline__ void part_body(
    int pb, int l,
    const float* __restrict__ em, const float* __restrict__ trans,
    const float* __restrict__ mask, float* __restrict__ out)
{
    const int c   = pb & (CRF_NC - 1);
    const int grp = pb / CRF_NC;
    const int lj  = l & 15;
    const int g   = l >> 4;

    short8 Af[4][2];
    UNR for (int mt = 0; mt < 4; ++mt)
      UNR for (int kc = 0; kc < 2; ++kc) {
        short8 f;
        UNR for (int e = 0; e < 8; ++e) {
            int L = kc * 32 + (e >> 2) * 16 + g * 4 + (e & 3);
            f[e] = (short)f2bf(__expf(trans[L * CRF_L + mt * 16 + lj]));
        }
        Af[mt][kc] = f;
      }

    const int b = grp * GRP + lj;
    const float* erow = em + (size_t)b * (CRF_S * CRF_L) + g * 4;
    const float* mrow = mask + (size_t)b * CRF_S;

    const int t_mid = CRF_CK * c;
    int t1, te;
    float val[4][4];
    if (c == 0) {
        t1 = 1; te = CRF_CK;          // 16 steps (multiple of 4)
        UNR for (int mt = 0; mt < 4; ++mt)
          UNR for (int r = 0; r < 4; ++r) {
            int n = mt * 16 + g * 4 + r;
            val[mt][r] = __expf(trans[CRF_BOS * CRF_L + n] + erow[mt * 16 + r]);
          }
    } else {
        te = (c == CRF_NC - 1) ? (CRF_S - 1) : (t_mid + CRF_CK);
        t1 = te - 19;                  // 20 steps (burn-in 4-5, multiple of 4)
        UNR for (int mt = 0; mt < 4; ++mt)
          UNR for (int r = 0; r < 4; ++r) val[mt][r] = 1.0f;
    }

    float Clog = 0.f, a0 = 0.f;

    // prologue: raw P,Q,R,S = em[t1..t1+3]; masks mb0..mb3; eeX = exp(P)
    float eeX[16], eeY[16];
    float rawP[16], rawQ[16], rawR[16], rawS[16];
    float mb0, mb1, mb2, mb3;
    {
        int ta0 = t1,     tb0 = t1;
        int ta1 = t1 + 1, tb1 = t1 + 1;
        int ta2 = t1 + 2, tb2 = t1 + 2;
        int ta3 = t1 + 3, tb3 = t1 + 3;
        if (ta1 > CRF_S - 1) ta1 = CRF_S - 1;
        if (ta2 > CRF_S - 1) ta2 = CRF_S - 1;
        if (ta3 > CRF_S - 1) ta3 = CRF_S - 1;
        if (tb1 > te) tb1 = te;
        if (tb2 > te) tb2 = te;
        if (tb3 > te) tb3 = te;
        mb0 = mrow[tb0]; mb1 = mrow[tb1]; mb2 = mrow[tb2]; mb3 = mrow[tb3];
        UNR for (int mt = 0; mt < 4; ++mt) {
            f32x4 r0 = *(const f32x4*)(erow + (size_t)ta0 * CRF_L + mt * 16);
            f32x4 r1 = *(const f32x4*)(erow + (size_t)ta1 * CRF_L + mt * 16);
            f32x4 r2 = *(const f32x4*)(erow + (size_t)ta2 * CRF_L + mt * 16);
            f32x4 r3 = *(const f32x4*)(erow + (size_t)ta3 * CRF_L + mt * 16);
            UNR for (int r = 0; r < 4; ++r) {
                rawP[mt * 4 + r] = r0[r];
                rawQ[mt * 4 + r] = r1[r];
                rawR[mt * 4 + r] = r2[r];
                rawS[mt * 4 + r] = r3[r];
            }
        }
        UNR for (int i = 0; i < 16; ++i) eeX[i] = __expf(rawP[i]);
    }

    // main loop: steps are a multiple of 4 for every chunk
    for (int t = t1; t + 3 <= te; t += 4) {
        STEP4(t,     eeX, eeY, rawQ, rawP, mb0);
        STEP4(t + 1, eeY, eeX, rawR, rawQ, mb1);
        STEP4(t + 2, eeX, eeY, rawS, rawR, mb2);
        STEP4(t + 3, eeY, eeX, rawP, rawS, mb3);
    }

    float a1;
    if (c == CRF_NC - 1) {
        float s = 0.f;
        UNR for (int mt = 0; mt < 4; ++mt)
          UNR for (int r = 0; r < 4; ++r)
            s += val[mt][r] * __expf(trans[(mt * 16 + g * 4 + r) * CRF_L + CRF_EOS]);
        s += __shfl_xor(s, 16);
        s += __shfl_xor(s, 32);
        a1 = Clog + __logf(s);
    } else {
        a1 = Clog + __logf(__shfl(val[0][0], l & 15));
    }
    if (l < 16) atomicAdd(&out[b], a1 - a0);
}

// ---------- fused kernel: part first, gold tail (R6 layout) -------------
__global__ __launch_bounds__(64) void crf_fused(
    const float* __restrict__ em, const float* __restrict__ trans,
    const int* __restrict__ tags, const float* __restrict__ mask,
    float* __restrict__ out)
{
    const int bid = blockIdx.x;
    const int l   = threadIdx.x;
    if (bid < PART_BLOCKS) {
        part_body(bid, l, em, trans, mask, out);
    } else {
        gold_body(bid - PART_BLOCKS, l, em, trans, tags, mask, out);
    }
}

extern "C" void kernel_launch(void* const* d_in, const int* in_sizes, int n_in,
                              void* d_out, int out_size, void* d_ws, size_t ws_size,
                              hipStream_t stream) {
    const float* em    = (const float*)d_in[0];
    const float* trans = (const float*)d_in[1];
    const int*   tags  = (const int*)d_in[2];
    const float* mask  = (const float*)d_in[3];
    float* out  = (float*)d_out;

    hipMemsetAsync(out, 0, CRF_B * sizeof(float), stream);
    crf_fused<<<PART_BLOCKS + CRF_B, 64, 0, stream>>>(em, trans, tags, mask, out);
}

// Round 11
// 48.971 us; speedup vs baseline: 1.2474x; 1.0781x over previous
//
#include <hip/hip_runtime.h>
#include <hip/hip_bf16.h>

#define CRF_B 512
#define CRF_S 1024
#define CRF_L 64
#define CRF_BOS 61
#define CRF_EOS 62
#define CRF_NC 64                  // chunks per sequence
#define CRF_CK (CRF_S / CRF_NC)    // 16 steps per chunk
#define CRF_W 2                    // burn-in steps (validated absmax 0.0 in R9)
#define GRP 16                     // batches per wave
#define PART_BLOCKS ((CRF_B / GRP) * CRF_NC)   // 2048

typedef __attribute__((ext_vector_type(8))) short short8;
typedef __attribute__((ext_vector_type(4))) float f32x4;
typedef __attribute__((ext_vector_type(4), aligned(4))) float f32x4u;  // 4B-aligned
#define UNR _Pragma("unroll")

__device__ __forceinline__ unsigned short f2bf(float x) {
    union { __hip_bfloat16 h; unsigned short u; } cv;
    cv.h = __float2bfloat16(x);
    return cv.u;
}

// -------------------- gold scores (R6 version, atomic output) -----------
__device__ __forceinline__ void gold_body(
    int b, int l,
    const float* __restrict__ em, const float* __restrict__ trans,
    const int* __restrict__ tags, const float* __restrict__ mask,
    float* __restrict__ out)
{
    const float* emb = em + (size_t)b * CRF_S * CRF_L;
    const int*   tg  = tags + (size_t)b * CRF_S;
    const float* mk  = mask + (size_t)b * CRF_S;

    float acc = 0.f, msum = 0.f;
    for (int t = l; t < CRF_S; t += 64) {
        float m = mk[t];
        msum += m;
        if (t >= 1) {
            int ct = tg[t];
            int pt = tg[t - 1];
            acc += (emb[(size_t)t * CRF_L + ct] + trans[pt * CRF_L + ct]) * m;
        }
    }
    UNR
    for (int off = 32; off; off >>= 1) {
        acc  += __shfl_xor(acc, off);
        msum += __shfl_xor(msum, off);
    }
    if (l == 0) {
        int t0 = tg[0];
        acc += trans[CRF_BOS * CRF_L + t0] + emb[t0];
        int last = (int)(msum + 0.5f) - 1;
        int lt = tg[last];
        acc += trans[lt * CRF_L + CRF_EOS];
        atomicAdd(&out[b], -acc);
    }
}

// -------------------- MFMA chunked log partition ------------------------
// S' = E_perm(A-op, const) @ S(B-op); MFMA C/D layout IS next step's B-frag.
// 4 rotating em register buffers (loads for T+4 at step T); exp 1 ahead;
// masks one f32x4 per 4-step group (scalar loads only in the <=3-step tail).
#define STEP4(T, eeU, eeV, RE, RL, MS)                                          \
  {                                                                             \
    short8 Bf0, Bf1;                                                            \
    UNR for (int e = 0; e < 8; ++e) {                                           \
        Bf0[e] = (short)f2bf(val[e >> 2][e & 3]);                               \
        Bf1[e] = (short)f2bf(val[2 + (e >> 2)][e & 3]);                         \
    }                                                                           \
    UNR for (int mt = 0; mt < 4; ++mt) {                                        \
        f32x4 acc = {0.f, 0.f, 0.f, 0.f};                                       \
        acc = __builtin_amdgcn_mfma_f32_16x16x32_bf16(Af[mt][0], Bf0, acc, 0, 0, 0); \
        acc = __builtin_amdgcn_mfma_f32_16x16x32_bf16(Af[mt][1], Bf1, acc, 0, 0, 0); \
        UNR for (int r = 0; r < 4; ++r) {                                       \
            float nv = acc[r] * eeU[mt * 4 + r];                                \
            val[mt][r] = ((MS) > 0.5f) ? nv : val[mt][r];                       \
        }                                                                       \
    }                                                                           \
    UNR for (int i = 0; i < 16; ++i) eeV[i] = __expf(RE[i]);                    \
    { int tl = (T) + 4; if (tl > CRF_S - 1) tl = CRF_S - 1;                     \
      UNR for (int mt = 0; mt < 4; ++mt) {                                      \
          f32x4 rv = *(const f32x4*)(erow + (size_t)tl * CRF_L + mt * 16);      \
          UNR for (int r = 0; r < 4; ++r) RL[mt * 4 + r] = rv[r];               \
      } }                                                                       \
    if (((T) & 7) == 0) {                                                       \
        float rsc = __shfl(val[0][0], l & 15);                                  \
        Clog += __logf(rsc);                                                    \
        float inv = 1.0f / rsc;                                                 \
        UNR for (int mt = 0; mt < 4; ++mt)                                      \
            UNR for (int r = 0; r < 4; ++r) val[mt][r] *= inv;                  \
    }                                                                           \
    if ((T) == t_mid) a0 = Clog + __logf(__shfl(val[0][0], l & 15));            \
  }

__device__ __forceinline__ void part_body(
    int pb, int l,
    const float* __restrict__ em, const float* __restrict__ trans,
    const float* __restrict__ mask, float* __restrict__ out)
{
    const int c   = pb & (CRF_NC - 1);
    const int grp = pb / CRF_NC;
    const int lj  = l & 15;
    const int g   = l >> 4;

    short8 Af[4][2];
    UNR for (int mt = 0; mt < 4; ++mt)
      UNR for (int kc = 0; kc < 2; ++kc) {
        short8 f;
        UNR for (int e = 0; e < 8; ++e) {
            int L = kc * 32 + (e >> 2) * 16 + g * 4 + (e & 3);
            f[e] = (short)f2bf(__expf(trans[L * CRF_L + mt * 16 + lj]));
        }
        Af[mt][kc] = f;
      }

    const int b = grp * GRP + lj;
    const float* erow = em + (size_t)b * (CRF_S * CRF_L) + g * 4;
    const float* mrow = mask + (size_t)b * CRF_S;

    const int t_mid = CRF_CK * c;
    int t1, te;
    float val[4][4];
    if (c == 0) {
        t1 = 1; te = CRF_CK;                       // 16 steps
        UNR for (int mt = 0; mt < 4; ++mt)
          UNR for (int r = 0; r < 4; ++r) {
            int n = mt * 16 + g * 4 + r;
            val[mt][r] = __expf(trans[CRF_BOS * CRF_L + n] + erow[mt * 16 + r]);
          }
    } else {
        te = (c == CRF_NC - 1) ? (CRF_S - 1) : (t_mid + CRF_CK);
        t1 = t_mid - CRF_W + 1;                    // 18 steps (17 for last chunk)
        UNR for (int mt = 0; mt < 4; ++mt)
          UNR for (int r = 0; r < 4; ++r) val[mt][r] = 1.0f;
    }

    float Clog = 0.f, a0 = 0.f;

    // prologue: raw P,Q,R,S = em[t1..t1+3]; masks mvA = mask[t1..t1+3]; eeX
    float eeX[16], eeY[16];
    float rawP[16], rawQ[16], rawR[16], rawS[16];
    f32x4 mvA, mvB;
    {
        mvA = *(const f32x4u*)(mrow + t1);         // t1 <= 1007, in bounds
        int ta1 = t1 + 1, ta2 = t1 + 2, ta3 = t1 + 3;
        if (ta1 > CRF_S - 1) ta1 = CRF_S - 1;
        if (ta2 > CRF_S - 1) ta2 = CRF_S - 1;
        if (ta3 > CRF_S - 1) ta3 = CRF_S - 1;
        UNR for (int mt = 0; mt < 4; ++mt) {
            f32x4 r0 = *(const f32x4*)(erow + (size_t)t1  * CRF_L + mt * 16);
            f32x4 r1 = *(const f32x4*)(erow + (size_t)ta1 * CRF_L + mt * 16);
            f32x4 r2 = *(const f32x4*)(erow + (size_t)ta2 * CRF_L + mt * 16);
            f32x4 r3 = *(const f32x4*)(erow + (size_t)ta3 * CRF_L + mt * 16);
            UNR for (int r = 0; r < 4; ++r) {
                rawP[mt * 4 + r] = r0[r];
                rawQ[mt * 4 + r] = r1[r];
                rawR[mt * 4 + r] = r2[r];
                rawS[mt * 4 + r] = r3[r];
            }
        }
        UNR for (int i = 0; i < 16; ++i) eeX[i] = __expf(rawP[i]);
    }

    // main loop: 4-step groups, one vector mask load per group
    int t = t1;
    for (; t + 3 <= te; t += 4) {
        {   // masks for next group (clamped base; values only used if it runs)
            int tb = t + 4; if (tb > CRF_S - 4) tb = CRF_S - 4;
            mvB = *(const f32x4u*)(mrow + tb);
        }
        STEP4(t,     eeX, eeY, rawQ, rawP, mvA[0]);
        STEP4(t + 1, eeY, eeX, rawR, rawQ, mvA[1]);
        STEP4(t + 2, eeX, eeY, rawS, rawR, mvA[2]);
        STEP4(t + 3, eeY, eeX, rawP, rawS, mvA[3]);
        mvA = mvB;
    }
    // tail (<=3 steps): exact scalar mask loads
    if (t <= te)     STEP4(t,     eeX, eeY, rawQ, rawP, mrow[t]);
    if (t + 1 <= te) STEP4(t + 1, eeY, eeX, rawR, rawQ, mrow[t + 1]);
    if (t + 2 <= te) STEP4(t + 2, eeX, eeY, rawS, rawR, mrow[t + 2]);

    float a1;
    if (c == CRF_NC - 1) {
        float s = 0.f;
        UNR for (int mt = 0; mt < 4; ++mt)
          UNR for (int r = 0; r < 4; ++r)
            s += val[mt][r] * __expf(trans[(mt * 16 + g * 4 + r) * CRF_L + CRF_EOS]);
        s += __shfl_xor(s, 16);
        s += __shfl_xor(s, 32);
        a1 = Clog + __logf(s);
    } else {
        a1 = Clog + __logf(__shfl(val[0][0], l & 15));
    }
    if (l < 16) atomicAdd(&out[b], a1 - a0);
}

// ---------- fused kernel: part first, gold tail (R6 layout) -------------
__global__ __launch_bounds__(64) void crf_fused(
    const float* __restrict__ em, const float* __restrict__ trans,
    const int* __restrict__ tags, const float* __restrict__ mask,
    float* __restrict__ out)
{
    const int bid = blockIdx.x;
    const int l   = threadIdx.x;
    if (bid < PART_BLOCKS) {
        part_body(bid, l, em, trans, mask, out);
    } else {
        gold_body(bid - PART_BLOCKS, l, em, trans, tags, mask, out);
    }
}

extern "C" void kernel_launch(void* const* d_in, const int* in_sizes, int n_in,
                              void* d_out, int out_size, void* d_ws, size_t ws_size,
                              hipStream_t stream) {
    const float* em    = (const float*)d_in[0];
    const float* trans = (const float*)d_in[1];
    const int*   tags  = (const int*)d_in[2];
    const float* mask  = (const float*)d_in[3];
    float* out  = (float*)d_out;

    hipMemsetAsync(out, 0, CRF_B * sizeof(float), stream);
    crf_fused<<<PART_BLOCKS + CRF_B, 64, 0, stream>>>(em, trans, tags, mask, out);
}

// Round 12
// 45.571 us; speedup vs baseline: 1.3404x; 1.0746x over previous
//
#include <hip/hip_runtime.h>
#include <hip/hip_bf16.h>

#define CRF_B 512
#define CRF_S 1024
#define CRF_L 64
#define CRF_BOS 61
#define CRF_EOS 62
#define CRF_NC 64                  // chunks per sequence
#define CRF_CK (CRF_S / CRF_NC)    // 16 steps per chunk
#define CRF_W 2                    // burn-in steps (validated absmax 0.0)
#define GRP 16                     // batches per wave
#define PART_BLOCKS ((CRF_B / GRP) * CRF_NC)   // 2048
#define GOLD_SPLIT 4               // gold waves per batch (validated in R8)
#define GOLD_BLOCKS (CRF_B * GOLD_SPLIT)       // 2048
#define GOLD_SPAN (CRF_S / GOLD_SPLIT)         // 256 steps per gold wave

typedef __attribute__((ext_vector_type(8))) short short8;
typedef __attribute__((ext_vector_type(4))) float f32x4;
typedef __attribute__((ext_vector_type(4), aligned(4))) float f32x4u;  // 4B-aligned
#define UNR _Pragma("unroll")

__device__ __forceinline__ unsigned short f2bf(float x) {
    union { __hip_bfloat16 h; unsigned short u; } cv;
    cv.h = __float2bfloat16(x);
    return cv.u;
}

// -------------------- gold scores (4-way split, tail position) ----------
// Split q covers t in [q*256, (q+1)*256). Locally detectable terms:
// transition/emission need (t-1, t); EOS attaches to the last masked
// position (m[t]==1 && (t==S-1 || m[t+1]==0)); BOS+em0 attaches to q==0.
__device__ __forceinline__ void gold_body(
    int b, int q, int l,
    const float* __restrict__ em, const float* __restrict__ trans,
    const int* __restrict__ tags, const float* __restrict__ mask,
    float* __restrict__ out)
{
    const float* emb = em + (size_t)b * CRF_S * CRF_L;
    const int*   tg  = tags + (size_t)b * CRF_S;
    const float* mk  = mask + (size_t)b * CRF_S;

    float acc = 0.f;
    const int t0 = q * GOLD_SPAN;
    UNR
    for (int it = 0; it < GOLD_SPAN / 64; ++it) {
        int t = t0 + it * 64 + l;
        float m = mk[t];
        int ct = tg[t];
        if (m > 0.5f && (t == CRF_S - 1 || mk[t + 1] <= 0.5f))
            acc += trans[ct * CRF_L + CRF_EOS];
        if (t >= 1) {
            int pt = tg[t - 1];
            acc += (emb[(size_t)t * CRF_L + ct] + trans[pt * CRF_L + ct]) * m;
        }
    }
    UNR
    for (int off = 32; off; off >>= 1) acc += __shfl_xor(acc, off);
    if (l == 0) {
        if (q == 0) {
            int tt0 = tg[0];
            acc += trans[CRF_BOS * CRF_L + tt0] + emb[tt0];
        }
        atomicAdd(&out[b], -acc);
    }
}

// -------------------- MFMA chunked log partition (R11, unchanged) -------
#define STEP4(T, eeU, eeV, RE, RL, MS)                                          \
  {                                                                             \
    short8 Bf0, Bf1;                                                            \
    UNR for (int e = 0; e < 8; ++e) {                                           \
        Bf0[e] = (short)f2bf(val[e >> 2][e & 3]);                               \
        Bf1[e] = (short)f2bf(val[2 + (e >> 2)][e & 3]);                         \
    }                                                                           \
    UNR for (int mt = 0; mt < 4; ++mt) {                                        \
        f32x4 acc = {0.f, 0.f, 0.f, 0.f};                                       \
        acc = __builtin_amdgcn_mfma_f32_16x16x32_bf16(Af[mt][0], Bf0, acc, 0, 0, 0); \
        acc = __builtin_amdgcn_mfma_f32_16x16x32_bf16(Af[mt][1], Bf1, acc, 0, 0, 0); \
        UNR for (int r = 0; r < 4; ++r) {                                       \
            float nv = acc[r] * eeU[mt * 4 + r];                                \
            val[mt][r] = ((MS) > 0.5f) ? nv : val[mt][r];                       \
        }                                                                       \
    }                                                                           \
    UNR for (int i = 0; i < 16; ++i) eeV[i] = __expf(RE[i]);                    \
    { int tl = (T) + 4; if (tl > CRF_S - 1) tl = CRF_S - 1;                     \
      UNR for (int mt = 0; mt < 4; ++mt) {                                      \
          f32x4 rv = *(const f32x4*)(erow + (size_t)tl * CRF_L + mt * 16);      \
          UNR for (int r = 0; r < 4; ++r) RL[mt * 4 + r] = rv[r];               \
      } }                                                                       \
    if (((T) & 7) == 0) {                                                       \
        float rsc = __shfl(val[0][0], l & 15);                                  \
        Clog += __logf(rsc);                                                    \
        float inv = 1.0f / rsc;                                                 \
        UNR for (int mt = 0; mt < 4; ++mt)                                      \
            UNR for (int r = 0; r < 4; ++r) val[mt][r] *= inv;                  \
    }                                                                           \
    if ((T) == t_mid) a0 = Clog + __logf(__shfl(val[0][0], l & 15));            \
  }

__device__ __forceinline__ void part_body(
    int pb, int l,
    const float* __restrict__ em, const float* __restrict__ trans,
    const float* __restrict__ mask, float* __restrict__ out)
{
    const int c   = pb & (CRF_NC - 1);
    const int grp = pb / CRF_NC;
    const int lj  = l & 15;
    const int g   = l >> 4;

    short8 Af[4][2];
    UNR for (int mt = 0; mt < 4; ++mt)
      UNR for (int kc = 0; kc < 2; ++kc) {
        short8 f;
        UNR for (int e = 0; e < 8; ++e) {
            int L = kc * 32 + (e >> 2) * 16 + g * 4 + (e & 3);
            f[e] = (short)f2bf(__expf(trans[L * CRF_L + mt * 16 + lj]));
        }
        Af[mt][kc] = f;
      }

    const int b = grp * GRP + lj;
    const float* erow = em + (size_t)b * (CRF_S * CRF_L) + g * 4;
    const float* mrow = mask + (size_t)b * CRF_S;

    const int t_mid = CRF_CK * c;
    int t1, te;
    float val[4][4];
    if (c == 0) {
        t1 = 1; te = CRF_CK;
        UNR for (int mt = 0; mt < 4; ++mt)
          UNR for (int r = 0; r < 4; ++r) {
            int n = mt * 16 + g * 4 + r;
            val[mt][r] = __expf(trans[CRF_BOS * CRF_L + n] + erow[mt * 16 + r]);
          }
    } else {
        te = (c == CRF_NC - 1) ? (CRF_S - 1) : (t_mid + CRF_CK);
        t1 = t_mid - CRF_W + 1;
        UNR for (int mt = 0; mt < 4; ++mt)
          UNR for (int r = 0; r < 4; ++r) val[mt][r] = 1.0f;
    }

    float Clog = 0.f, a0 = 0.f;

    float eeX[16], eeY[16];
    float rawP[16], rawQ[16], rawR[16], rawS[16];
    f32x4 mvA, mvB;
    {
        mvA = *(const f32x4u*)(mrow + t1);
        int ta1 = t1 + 1, ta2 = t1 + 2, ta3 = t1 + 3;
        if (ta1 > CRF_S - 1) ta1 = CRF_S - 1;
        if (ta2 > CRF_S - 1) ta2 = CRF_S - 1;
        if (ta3 > CRF_S - 1) ta3 = CRF_S - 1;
        UNR for (int mt = 0; mt < 4; ++mt) {
            f32x4 r0 = *(const f32x4*)(erow + (size_t)t1  * CRF_L + mt * 16);
            f32x4 r1 = *(const f32x4*)(erow + (size_t)ta1 * CRF_L + mt * 16);
            f32x4 r2 = *(const f32x4*)(erow + (size_t)ta2 * CRF_L + mt * 16);
            f32x4 r3 = *(const f32x4*)(erow + (size_t)ta3 * CRF_L + mt * 16);
            UNR for (int r = 0; r < 4; ++r) {
                rawP[mt * 4 + r] = r0[r];
                rawQ[mt * 4 + r] = r1[r];
                rawR[mt * 4 + r] = r2[r];
                rawS[mt * 4 + r] = r3[r];
            }
        }
        UNR for (int i = 0; i < 16; ++i) eeX[i] = __expf(rawP[i]);
    }

    int t = t1;
    for (; t + 3 <= te; t += 4) {
        {
            int tb = t + 4; if (tb > CRF_S - 4) tb = CRF_S - 4;
            mvB = *(const f32x4u*)(mrow + tb);
        }
        STEP4(t,     eeX, eeY, rawQ, rawP, mvA[0]);
        STEP4(t + 1, eeY, eeX, rawR, rawQ, mvA[1]);
        STEP4(t + 2, eeX, eeY, rawS, rawR, mvA[2]);
        STEP4(t + 3, eeY, eeX, rawP, rawS, mvA[3]);
        mvA = mvB;
    }
    if (t <= te)     STEP4(t,     eeX, eeY, rawQ, rawP, mrow[t]);
    if (t + 1 <= te) STEP4(t + 1, eeY, eeX, rawR, rawQ, mrow[t + 1]);
    if (t + 2 <= te) STEP4(t + 2, eeX, eeY, rawS, rawR, mrow[t + 2]);

    float a1;
    if (c == CRF_NC - 1) {
        float s = 0.f;
        UNR for (int mt = 0; mt < 4; ++mt)
          UNR for (int r = 0; r < 4; ++r)
            s += val[mt][r] * __expf(trans[(mt * 16 + g * 4 + r) * CRF_L + CRF_EOS]);
        s += __shfl_xor(s, 16);
        s += __shfl_xor(s, 32);
        a1 = Clog + __logf(s);
    } else {
        a1 = Clog + __logf(__shfl(val[0][0], l & 15));
    }
    if (l < 16) atomicAdd(&out[b], a1 - a0);
}

// ---------- fused kernel: part first, SPLIT gold tail -------------------
__global__ __launch_bounds__(64) void crf_fused(
    const float* __restrict__ em, const float* __restrict__ trans,
    const int* __restrict__ tags, const float* __restrict__ mask,
    float* __restrict__ out)
{
    const int bid = blockIdx.x;
    const int l   = threadIdx.x;
    if (bid < PART_BLOCKS) {
        part_body(bid, l, em, trans, mask, out);
    } else {
        const int gb = bid - PART_BLOCKS;
        gold_body(gb >> 2, gb & 3, l, em, trans, tags, mask, out);
    }
}

extern "C" void kernel_launch(void* const* d_in, const int* in_sizes, int n_in,
                              void* d_out, int out_size, void* d_ws, size_t ws_size,
                              hipStream_t stream) {
    const float* em    = (const float*)d_in[0];
    const float* trans = (const float*)d_in[1];
    const int*   tags  = (const int*)d_in[2];
    const float* mask  = (const float*)d_in[3];
    float* out  = (float*)d_out;

    hipMemsetAsync(out, 0, CRF_B * sizeof(float), stream);
    crf_fused<<<PART_BLOCKS + GOLD_BLOCKS, 64, 0, stream>>>(em, trans, tags, mask, out);
}